// Round 5
// baseline (1476.920 us; speedup 1.0000x reference)
//
#include <hip/hip_runtime.h>
#include <hip/hip_bf16.h>

typedef __bf16 bf16_t;
typedef bf16_t bf16x8 __attribute__((ext_vector_type(8)));
typedef float f32x4 __attribute__((ext_vector_type(4)));
typedef ushort ushortx8 __attribute__((ext_vector_type(8)));

#define L_NUM 3
#define E_NUM 4
#define D_DIM 1024
#define R_DIM 64
#define B_ROWS 32768
#define BT 64            // rows per block: weight stream amortized over 64 rows (halves L2 bytes vs BT=32)
#define TPB 512          // 8 waves, 1 block/CU, 2 waves/SIMD
#define N1 272           // 256 V-cols + 4 gating cols + 12 zero pad

#define VT_ELEMS (L_NUM * N1 * D_DIM)            // 835584
#define UT_ELEMS (L_NUM * D_DIM * 256)           // 786432
#define CB_ELEMS (L_NUM * E_NUM * R_DIM * R_DIM) // 49152
#define PACK_TOTAL (VT_ELEMS + UT_ELEMS + CB_ELEMS)

#define MFMA16(a, b, c) __builtin_amdgcn_mfma_f32_16x16x32_bf16((a), (b), (c), 0, 0, 0)

__device__ __forceinline__ ushort f2b(float f) {
  union { float f; unsigned u; } x; x.f = f;
  unsigned r = (x.u + 0x7fffu + ((x.u >> 16) & 1u)) >> 16;  // RNE
  return (ushort)r;
}
__device__ __forceinline__ float b2f(ushort h) {
  union { unsigned u; float f; } x; x.u = ((unsigned)h) << 16;
  return x.f;
}
__device__ __forceinline__ float tanh_fast(float x) {
  float cx = fminf(fmaxf(x, -15.f), 15.f);
  float e = __expf(2.f * cx);
  return (e - 1.f) / (e + 1.f);
}

// XOR swizzle: 16B granules within a row, granule ^= (row&7). Write-side and read-side both
// apply the same involution (both-sides-or-neither rule).
__device__ __forceinline__ int xl_addr(int row, int col) {   // ushort index, [64][1024]
  return row * 1024 + ((((col >> 3) ^ (row & 7)) << 3) | (col & 7));
}
__device__ __forceinline__ int t1_addr(int row, int col) {   // ushort index, [64][256]
  return row * 256 + ((((col >> 3) ^ (row & 7)) << 3) | (col & 7));
}

// ---------------- weight prepack (single launch): f32 -> bf16, B^T ([N][K]) layouts ----------------

__global__ void pack_all_kernel(const float* __restrict__ U, const float* __restrict__ V,
                                const float* __restrict__ C, const float* __restrict__ gw,
                                ushort* __restrict__ vt, ushort* __restrict__ ut,
                                ushort* __restrict__ cb) {
  int idx = blockIdx.x * 256 + threadIdx.x;
  if (idx < VT_ELEMS) {
    int d = idx & (D_DIM - 1);
    int n = (idx >> 10) % N1;
    int l = idx / (N1 * D_DIM);
    float val = 0.f;
    if (n < 256) {
      int e = n >> 6, r = n & 63;
      val = V[(((l * E_NUM + e) * D_DIM) + d) * R_DIM + r];   // Vt[l][e*64+r][d] = V[l,e,d,r]
    } else if (n < 260) {
      val = gw[(n - 256) * D_DIM + d];                        // gating cols
    }
    vt[idx] = f2b(val);
  } else if (idx < VT_ELEMS + UT_ELEMS) {
    int i2 = idx - VT_ELEMS;
    int er = i2 & 255;
    int d = (i2 >> 8) & (D_DIM - 1);
    int l = i2 >> 18;
    int e = er >> 6, r = er & 63;
    ut[i2] = f2b(U[((l * E_NUM + e) * D_DIM + d) * R_DIM + r]);  // Ut[l][d][e*64+r]
  } else if (idx < PACK_TOTAL) {
    int i3 = idx - VT_ELEMS - UT_ELEMS;
    cb[i3] = f2b(C[i3]);   // C[l,e,r,s] already is Bt[n=r][k=s]
  }
}

// ---------------- fused 3-layer CrossNet: each block owns 64 rows end-to-end ----------------
// x_L = x0 + x0 * Sum_l(S_l + bias_l). The f32 carry A = Sum(S+b) lives in the `out` buffer
// (per-element, same thread reads/writes across layers -> no fences; f32 roundtrip is exact,
// so the result is bit-identical to r4's A-in-register formulation, which passed).
// r3/r4 lesson: a 128-f32 per-thread register carry across MFMA phases ALWAYS spills
// (r3: 2.5 GB scratch traffic, r4: 1.6 GB). Register demand here is ~110 live f32 -> no spill.
// LDS = xl[64][1024] + t1[64][256] = 160 KB exactly, XOR-swizzled; glog overlaid in xl's dead window.

__global__ __launch_bounds__(TPB, 1) void crossnet_fused(
    const float* __restrict__ inputs, const float* __restrict__ bias,
    const ushort* __restrict__ Vt, const ushort* __restrict__ Ut,
    const ushort* __restrict__ Cb, float* __restrict__ out) {
  __shared__ ushort xl[BT * 1024];   // 131072 B, x_l bf16 (swizzled); bytes [0,1024) double as glog
  __shared__ ushort t1[BT * 256];    // 32768 B, v1 then w (swizzled)

  const int tid = threadIdx.x;
  const int wave = tid >> 6;      // 0..7
  const int lane = tid & 63;
  const int l15 = lane & 15;
  const int quad = lane >> 4;
  const int s = l15 & 7;          // swizzle XOR for frag reads (rows = m*16 + l15)
  const long rowbase = (long)blockIdx.x * BT;

  // ---- stage inputs -> xl bf16 (coalesced, 16B granule writes): 64 rows x 128 granules ----
  #pragma unroll
  for (int i = 0; i < 16; ++i) {
    int gid = tid + i * TPB;        // granule id in [64][128]
    int row = gid >> 7;
    int g = gid & 127;
    const float4* ip = (const float4*)(inputs + (rowbase + row) * D_DIM);
    float4 v0 = ip[g * 2];
    float4 v1 = ip[g * 2 + 1];
    ushortx8 h;
    h[0] = f2b(v0.x); h[1] = f2b(v0.y); h[2] = f2b(v0.z); h[3] = f2b(v0.w);
    h[4] = f2b(v1.x); h[5] = f2b(v1.y); h[6] = f2b(v1.z); h[7] = f2b(v1.w);
    *(ushortx8*)&xl[row * 1024 + ((g ^ (row & 7)) << 3)] = h;
  }
  __syncthreads();

  const f32x4 zf = {0.f, 0.f, 0.f, 0.f};
  const int eC = wave >> 1;   // phase-C expert
  const int nh = wave & 1;    // phase-C 32-col half within expert

  for (int l = 0; l < L_NUM; ++l) {
    const ushort* vtl = Vt + l * N1 * D_DIM;
    const ushort* utl = Ut + l * D_DIM * 256;
    const ushort* cbl = Cb + l * E_NUM * R_DIM * R_DIM;

    // ========== Phase A: GEMM1 v1[64,256] = tanh(xl @ V); wave 7 also the gating tile ==========
    f32x4 acc1[2][4];   // [t: 16-col tile][m: 16-row tile]
    #pragma unroll
    for (int t = 0; t < 2; ++t)
      #pragma unroll
      for (int m = 0; m < 4; ++m) acc1[t][m] = zf;
    f32x4 accg[4];      // gating logits (wave 7 only; dead regs elsewhere)
    #pragma unroll
    for (int m = 0; m < 4; ++m) accg[m] = zf;

    const ushort* vb0 = vtl + (wave * 32 + l15) * D_DIM + quad * 8;
    const ushort* vb1 = vb0 + 16 * D_DIM;
    if (wave == 7) {
      const ushort* vbg = vtl + (256 + l15) * D_DIM + quad * 8;
      #pragma unroll 4
      for (int k0 = 0; k0 < D_DIM; k0 += 32) {
        bf16x8 b0 = *(const bf16x8*)(vb0 + k0);
        bf16x8 b1 = *(const bf16x8*)(vb1 + k0);
        bf16x8 bg = *(const bf16x8*)(vbg + k0);
        #pragma unroll
        for (int m = 0; m < 4; ++m) {
          bf16x8 a = *(const bf16x8*)&xl[(m * 16 + l15) * 1024 + ((((k0 >> 3) + quad) ^ s) << 3)];
          acc1[0][m] = MFMA16(a, b0, acc1[0][m]);
          acc1[1][m] = MFMA16(a, b1, acc1[1][m]);
          accg[m]    = MFMA16(a, bg, accg[m]);
        }
      }
    } else {
      #pragma unroll 4
      for (int k0 = 0; k0 < D_DIM; k0 += 32) {
        bf16x8 b0 = *(const bf16x8*)(vb0 + k0);
        bf16x8 b1 = *(const bf16x8*)(vb1 + k0);
        #pragma unroll
        for (int m = 0; m < 4; ++m) {
          bf16x8 a = *(const bf16x8*)&xl[(m * 16 + l15) * 1024 + ((((k0 >> 3) + quad) ^ s) << 3)];
          acc1[0][m] = MFMA16(a, b0, acc1[0][m]);
          acc1[1][m] = MFMA16(a, b1, acc1[1][m]);
        }
      }
    }

    // epilogue A: v1 = tanh -> t1 (bf16, swizzled)
    #pragma unroll
    for (int t = 0; t < 2; ++t)
      #pragma unroll
      for (int m = 0; m < 4; ++m)
        #pragma unroll
        for (int rg = 0; rg < 4; ++rg) {
          int row = m * 16 + quad * 4 + rg;
          t1[t1_addr(row, wave * 32 + t * 16 + l15)] = f2b(tanh_fast(acc1[t][m][rg]));
        }
    __syncthreads();   // BARRIER1: v1 visible; all xl reads done -> xl row-0 region dead

    // gating logits -> glog overlay (dead xl bytes [0,1024)); consumed after BARRIER2
    if (wave == 7 && l15 < 4) {
      float* glog = (float*)xl;
      #pragma unroll
      for (int m = 0; m < 4; ++m)
        #pragma unroll
        for (int rg = 0; rg < 4; ++rg)
          glog[(m * 16 + quad * 4 + rg) * 4 + l15] = accg[m][rg];
    }

    // ========== Phase C: block-diag v2 = tanh(C @ v1) ==========
    f32x4 acc2[2][4];
    #pragma unroll
    for (int t = 0; t < 2; ++t)
      #pragma unroll
      for (int m = 0; m < 4; ++m) acc2[t][m] = zf;
    const ushort* cb0 = cbl + (eC * 64 + nh * 32 + l15) * 64 + quad * 8;
    const ushort* cb1 = cb0 + 16 * 64;
    #pragma unroll
    for (int k0 = 0; k0 < 64; k0 += 32) {
      bf16x8 b0 = *(const bf16x8*)(cb0 + k0);
      bf16x8 b1 = *(const bf16x8*)(cb1 + k0);
      #pragma unroll
      for (int m = 0; m < 4; ++m) {
        bf16x8 a = *(const bf16x8*)&t1[(m * 16 + l15) * 256 + (((eC * 8 + (k0 >> 3) + quad) ^ s) << 3)];
        acc2[0][m] = MFMA16(a, b0, acc2[0][m]);
        acc2[1][m] = MFMA16(a, b1, acc2[1][m]);
      }
    }
    __syncthreads();   // BARRIER2: all v1 reads done (t1 reusable); glog visible

    // w-epilogue: per-thread softmax from glog, w = gate * tanh(v2) -> t1
    {
      const float* glog = (const float*)xl;
      #pragma unroll
      for (int m = 0; m < 4; ++m)
        #pragma unroll
        for (int rg = 0; rg < 4; ++rg) {
          int row = m * 16 + quad * 4 + rg;
          float4 gl = *(const float4*)&glog[row * 4];
          float mx = fmaxf(fmaxf(gl.x, gl.y), fmaxf(gl.z, gl.w));
          float e0 = __expf(gl.x - mx), e1 = __expf(gl.y - mx);
          float e2 = __expf(gl.z - mx), e3 = __expf(gl.w - mx);
          float ge = (eC == 0) ? e0 : (eC == 1) ? e1 : (eC == 2) ? e2 : e3;
          float g = ge / (e0 + e1 + e2 + e3);
          #pragma unroll
          for (int t = 0; t < 2; ++t)
            t1[t1_addr(row, eC * 64 + nh * 32 + t * 16 + l15)] = f2b(g * tanh_fast(acc2[t][m][rg]));
        }
    }
    __syncthreads();   // BARRIER3: w ready

    // ========== Phase D: GEMM2 S[64,1024] = w[64,256] @ Ut^T, 4 passes of 32 cols ==========
    #pragma unroll
    for (int p = 0; p < 4; ++p) {
      f32x4 acc3[2][4];
      #pragma unroll
      for (int nt = 0; nt < 2; ++nt)
        #pragma unroll
        for (int m = 0; m < 4; ++m) acc3[nt][m] = zf;
      const ushort* ub0 = utl + (wave * 128 + p * 32 + l15) * 256 + quad * 8;
      const ushort* ub1 = ub0 + 16 * 256;
      #pragma unroll 4
      for (int k0 = 0; k0 < 256; k0 += 32) {
        bf16x8 b0 = *(const bf16x8*)(ub0 + k0);
        bf16x8 b1 = *(const bf16x8*)(ub1 + k0);
        #pragma unroll
        for (int m = 0; m < 4; ++m) {
          bf16x8 a = *(const bf16x8*)&t1[(m * 16 + l15) * 256 + ((((k0 >> 3) + quad) ^ s) << 3)];
          acc3[0][m] = MFMA16(a, b0, acc3[0][m]);
          acc3[1][m] = MFMA16(a, b1, acc3[1][m]);
        }
      }
      // epilogue pass p: A-carry lives in out[] (f32, exact). An = Aprev + (S + bias).
      // l<2: out=An, xl=f2b(xin + x0*An). l==2: out = xin + x0*An (final, f32 base term).
      #pragma unroll
      for (int nt = 0; nt < 2; ++nt) {
        int col = wave * 128 + p * 32 + nt * 16 + l15;
        float bv = bias[l * D_DIM + col];
        #pragma unroll
        for (int m = 0; m < 4; ++m)
          #pragma unroll
          for (int rg = 0; rg < 4; ++rg) {
            int row = m * 16 + quad * 4 + rg;
            long gidx = (rowbase + row) * D_DIM + col;
            float xin = inputs[gidx];
            float x0 = b2f(f2b(xin));                  // bf16 x0 product term (r0/r3/r4 numerics)
            float Aprev = (l == 0) ? 0.f : out[gidx];
            float An = Aprev + (acc3[nt][m][rg] + bv);
            if (l == L_NUM - 1) {
              out[gidx] = xin + x0 * An;               // final: f32 base term
            } else {
              out[gidx] = An;                          // f32 carry through global (exact roundtrip)
              xl[xl_addr(row, col)] = f2b(xin + x0 * An);
            }
          }
      }
    }
    __syncthreads();   // BARRIER4: xl_new complete; t1 free for next layer's v1
  }
}

extern "C" void kernel_launch(void* const* d_in, const int* in_sizes, int n_in,
                              void* d_out, int out_size, void* d_ws, size_t ws_size,
                              hipStream_t stream) {
  (void)in_sizes; (void)n_in; (void)out_size; (void)ws_size;
  const float* inputs = (const float*)d_in[0];
  const float* U      = (const float*)d_in[1];
  const float* V      = (const float*)d_in[2];
  const float* C      = (const float*)d_in[3];
  const float* gw     = (const float*)d_in[4];
  const float* bias   = (const float*)d_in[5];
  float* out = (float*)d_out;

  ushort* vt = (ushort*)d_ws;          // 3*272*1024 bf16
  ushort* ut = vt + VT_ELEMS;          // 3*1024*256 bf16
  ushort* cb = ut + UT_ELEMS;          // 3*4*64*64  bf16

  pack_all_kernel<<<(PACK_TOTAL + 255) / 256, 256, 0, stream>>>(U, V, C, gw, vt, ut, cb);

  crossnet_fused<<<B_ROWS / BT, TPB, 0, stream>>>(inputs, bias, vt, ut, cb, out);
}

// Round 6
// 1383.656 us; speedup vs baseline: 1.0674x; 1.0674x over previous
//
#include <hip/hip_runtime.h>
#include <hip/hip_bf16.h>

typedef __bf16 bf16_t;
typedef bf16_t bf16x8 __attribute__((ext_vector_type(8)));
typedef float f32x4 __attribute__((ext_vector_type(4)));
typedef ushort ushortx8 __attribute__((ext_vector_type(8)));

#define L_NUM 3
#define E_NUM 4
#define D_DIM 1024
#define R_DIM 64
#define B_ROWS 32768
#define BT 64            // rows per block: weight stream amortized over 64 rows
#define TPB 1024         // 16 waves -> per-thread A-carry is 64 f32 (registerable, r0-proven size)
#define N1 272           // 256 V-cols + 4 gating cols + 12 zero pad

#define VT_ELEMS (L_NUM * N1 * D_DIM)            // 835584
#define UT_ELEMS (L_NUM * D_DIM * 256)           // 786432
#define CB_ELEMS (L_NUM * E_NUM * R_DIM * R_DIM) // 49152
#define PACK_TOTAL (VT_ELEMS + UT_ELEMS + CB_ELEMS)

#define MFMA16(a, b, c) __builtin_amdgcn_mfma_f32_16x16x32_bf16((a), (b), (c), 0, 0, 0)

__device__ __forceinline__ ushort f2b(float f) {
  union { float f; unsigned u; } x; x.f = f;
  unsigned r = (x.u + 0x7fffu + ((x.u >> 16) & 1u)) >> 16;  // RNE
  return (ushort)r;
}
__device__ __forceinline__ float b2f(ushort h) {
  union { unsigned u; float f; } x; x.u = ((unsigned)h) << 16;
  return x.f;
}
__device__ __forceinline__ float tanh_fast(float x) {
  float cx = fminf(fmaxf(x, -15.f), 15.f);
  float e = __expf(2.f * cx);
  return (e - 1.f) / (e + 1.f);
}

// XOR swizzle: 16B granules within a row, granule ^= (row&7). Write-side and read-side both
// apply the same involution (both-sides-or-neither rule). Verified in r4/r5 (passed).
__device__ __forceinline__ int xl_addr(int row, int col) {   // ushort index, [64][1024]
  return row * 1024 + ((((col >> 3) ^ (row & 7)) << 3) | (col & 7));
}
__device__ __forceinline__ int t1_addr(int row, int col) {   // ushort index, [64][256]
  return row * 256 + ((((col >> 3) ^ (row & 7)) << 3) | (col & 7));
}

// ---------------- weight prepack (single launch): f32 -> bf16, B^T ([N][K]) layouts ----------------

__global__ void pack_all_kernel(const float* __restrict__ U, const float* __restrict__ V,
                                const float* __restrict__ C, const float* __restrict__ gw,
                                ushort* __restrict__ vt, ushort* __restrict__ ut,
                                ushort* __restrict__ cb) {
  int idx = blockIdx.x * 256 + threadIdx.x;
  if (idx < VT_ELEMS) {
    int d = idx & (D_DIM - 1);
    int n = (idx >> 10) % N1;
    int l = idx / (N1 * D_DIM);
    float val = 0.f;
    if (n < 256) {
      int e = n >> 6, r = n & 63;
      val = V[(((l * E_NUM + e) * D_DIM) + d) * R_DIM + r];   // Vt[l][e*64+r][d] = V[l,e,d,r]
    } else if (n < 260) {
      val = gw[(n - 256) * D_DIM + d];                        // gating cols
    }
    vt[idx] = f2b(val);
  } else if (idx < VT_ELEMS + UT_ELEMS) {
    int i2 = idx - VT_ELEMS;
    int er = i2 & 255;
    int d = (i2 >> 8) & (D_DIM - 1);
    int l = i2 >> 18;
    int e = er >> 6, r = er & 63;
    ut[i2] = f2b(U[((l * E_NUM + e) * D_DIM + d) * R_DIM + r]);  // Ut[l][d][e*64+r]
  } else if (idx < PACK_TOTAL) {
    int i3 = idx - VT_ELEMS - UT_ELEMS;
    cb[i3] = f2b(C[i3]);   // C[l,e,r,s] already is Bt[n=r][k=s]
  }
}

// ---------------- fused 3-layer CrossNet: each block owns 64 rows end-to-end ----------------
// x_L = x0 + x0 * Sum_l(S_l + bias_l). TPB=1024 -> per-thread carry A = 64 f32, kept in FOUR
// NAMED f32x4[4] arrays with hand-unrolled phase-D passes (all indices compile-time -> registers;
// rule-#20 insurance after r3/r4 spills). __launch_bounds__(1024,1): fitted rule
// VGPR_cap = 131072/(min_blocks*TPB) -> 128. Demand ~110 -> no spill, no memory carry.
// Gating spread over waves 12..15 (one m-tile each): no redundant B-stream (r2 mistake), no
// serial phase. LDS = xl[64][1024] + t1[64][256] = 160 KB exact, XOR-swizzled; glog overlaid
// in xl's dead window (r4/r5-verified). Numerics identical to r4/r5 (passed, absmax 0.03125).

__global__ __launch_bounds__(TPB, 1) void crossnet_fused(
    const float* __restrict__ inputs, const float* __restrict__ bias,
    const ushort* __restrict__ Vt, const ushort* __restrict__ Ut,
    const ushort* __restrict__ Cb, float* __restrict__ out) {
  __shared__ ushort xl[BT * 1024];   // 131072 B, x_l bf16 (swizzled); bytes [0,1024) double as glog
  __shared__ ushort t1[BT * 256];    // 32768 B, v1 then w (swizzled)

  const int tid = threadIdx.x;
  const int wave = tid >> 6;      // 0..15
  const int lane = tid & 63;
  const int l15 = lane & 15;
  const int quad = lane >> 4;
  const int s = l15 & 7;          // swizzle XOR for frag reads (rows = m*16 + l15)
  const long rowbase = (long)blockIdx.x * BT;

  // ---- stage inputs -> xl bf16 (coalesced, 16B granule writes): 64 rows x 128 granules ----
  #pragma unroll
  for (int i = 0; i < 8; ++i) {
    int gid = tid + i * TPB;        // granule id in [64][128]
    int row = gid >> 7;
    int g = gid & 127;
    const float4* ip = (const float4*)(inputs + (rowbase + row) * D_DIM);
    float4 v0 = ip[g * 2];
    float4 v1 = ip[g * 2 + 1];
    ushortx8 h;
    h[0] = f2b(v0.x); h[1] = f2b(v0.y); h[2] = f2b(v0.z); h[3] = f2b(v0.w);
    h[4] = f2b(v1.x); h[5] = f2b(v1.y); h[6] = f2b(v1.z); h[7] = f2b(v1.w);
    *(ushortx8*)&xl[row * 1024 + ((g ^ (row & 7)) << 3)] = h;
  }

  // ---- A-carry: 64 f32 in four NAMED arrays (static indexing only) ----
  f32x4 A0[4], A1[4], A2[4], A3[4];
  #pragma unroll
  for (int m = 0; m < 4; ++m) {
    A0[m] = (f32x4){0.f, 0.f, 0.f, 0.f};
    A1[m] = (f32x4){0.f, 0.f, 0.f, 0.f};
    A2[m] = (f32x4){0.f, 0.f, 0.f, 0.f};
    A3[m] = (f32x4){0.f, 0.f, 0.f, 0.f};
  }
  __syncthreads();

  const f32x4 zf = {0.f, 0.f, 0.f, 0.f};
  const int eC = wave >> 2;          // phase-C expert
  const int sub = wave & 3;          // phase-C 16-col group within expert
  const bool gwave = (wave >= 12);   // gating waves, one m-tile each
  const int gmt = wave - 12;         // gating m-tile (rows gmt*16..gmt*16+15)

  for (int l = 0; l < L_NUM; ++l) {
    const ushort* vtl = Vt + l * N1 * D_DIM;
    const ushort* utl = Ut + l * D_DIM * 256;
    const ushort* cbl = Cb + l * E_NUM * R_DIM * R_DIM;

    // ========== Phase A: GEMM1 v1[64,256] = tanh(xl @ V); waves 12..15 add one gating m-tile ====
    f32x4 acc1[4];
    #pragma unroll
    for (int m = 0; m < 4; ++m) acc1[m] = zf;
    f32x4 accg = zf;

    const ushort* vb0 = vtl + (wave * 16 + l15) * D_DIM + quad * 8;
    if (gwave) {
      const ushort* vbg = vtl + (256 + l15) * D_DIM + quad * 8;
      #pragma unroll 4
      for (int k0 = 0; k0 < D_DIM; k0 += 32) {
        bf16x8 b0 = *(const bf16x8*)(vb0 + k0);
        bf16x8 bg = *(const bf16x8*)(vbg + k0);
        int gcol = (((k0 >> 3) + quad) ^ s) << 3;
        #pragma unroll
        for (int m = 0; m < 4; ++m) {
          bf16x8 a = *(const bf16x8*)&xl[(m * 16 + l15) * 1024 + gcol];
          acc1[m] = MFMA16(a, b0, acc1[m]);
        }
        bf16x8 ag = *(const bf16x8*)&xl[(gmt * 16 + l15) * 1024 + gcol];
        accg = MFMA16(ag, bg, accg);
      }
    } else {
      #pragma unroll 4
      for (int k0 = 0; k0 < D_DIM; k0 += 32) {
        bf16x8 b0 = *(const bf16x8*)(vb0 + k0);
        int gcol = (((k0 >> 3) + quad) ^ s) << 3;
        #pragma unroll
        for (int m = 0; m < 4; ++m) {
          bf16x8 a = *(const bf16x8*)&xl[(m * 16 + l15) * 1024 + gcol];
          acc1[m] = MFMA16(a, b0, acc1[m]);
        }
      }
    }

    // epilogue A: v1 = tanh -> t1 (bf16, swizzled)
    #pragma unroll
    for (int m = 0; m < 4; ++m)
      #pragma unroll
      for (int rg = 0; rg < 4; ++rg) {
        int row = m * 16 + quad * 4 + rg;
        t1[t1_addr(row, wave * 16 + l15)] = f2b(tanh_fast(acc1[m][rg]));
      }
    __syncthreads();   // BARRIER1: v1 visible; all xl reads done -> xl dead until epilogue D

    // gating logits -> glog overlay (dead xl bytes [0,1024)); consumed after BARRIER2
    if (gwave && l15 < 4) {
      float* glog = (float*)xl;
      #pragma unroll
      for (int rg = 0; rg < 4; ++rg)
        glog[(gmt * 16 + quad * 4 + rg) * 4 + l15] = accg[rg];
    }

    // ========== Phase C: block-diag v2 = tanh(C @ v1) ==========
    f32x4 acc2[4];
    #pragma unroll
    for (int m = 0; m < 4; ++m) acc2[m] = zf;
    const ushort* cb0 = cbl + (eC * 64 + sub * 16 + l15) * 64 + quad * 8;
    #pragma unroll
    for (int k0 = 0; k0 < 64; k0 += 32) {
      bf16x8 b0 = *(const bf16x8*)(cb0 + k0);
      int gcol = ((eC * 8 + (k0 >> 3) + quad) ^ s) << 3;
      #pragma unroll
      for (int m = 0; m < 4; ++m) {
        bf16x8 a = *(const bf16x8*)&t1[(m * 16 + l15) * 256 + gcol];
        acc2[m] = MFMA16(a, b0, acc2[m]);
      }
    }
    __syncthreads();   // BARRIER2: all v1 reads done (t1 reusable); glog visible

    // w-epilogue: per-thread softmax from glog, w = gate * tanh(v2) -> t1
    {
      const float* glog = (const float*)xl;
      #pragma unroll
      for (int m = 0; m < 4; ++m)
        #pragma unroll
        for (int rg = 0; rg < 4; ++rg) {
          int row = m * 16 + quad * 4 + rg;
          float4 gl = *(const float4*)&glog[row * 4];
          float mx = fmaxf(fmaxf(gl.x, gl.y), fmaxf(gl.z, gl.w));
          float e0 = __expf(gl.x - mx), e1 = __expf(gl.y - mx);
          float e2 = __expf(gl.z - mx), e3 = __expf(gl.w - mx);
          float ge = (eC == 0) ? e0 : (eC == 1) ? e1 : (eC == 2) ? e2 : e3;
          float g = ge / (e0 + e1 + e2 + e3);
          t1[t1_addr(row, eC * 64 + sub * 16 + l15)] = f2b(g * tanh_fast(acc2[m][rg]));
        }
    }
    __syncthreads();   // BARRIER3: w ready

    // ========== Phase D: GEMM2 S[64,1024] = w[64,256] @ Ut^T, 4 hand-unrolled 16-col passes ====
    // Each pass: this wave's cols [wave*64 + P*16, +16). Named A-array per pass (static regs).
#define PHASE_D_PASS(P, AARR)                                                          \
    {                                                                                  \
      f32x4 acc3[4];                                                                   \
      _Pragma("unroll")                                                                \
      for (int m = 0; m < 4; ++m) acc3[m] = zf;                                        \
      const ushort* ub = utl + (wave * 64 + (P) * 16 + l15) * 256 + quad * 8;          \
      _Pragma("unroll 4")                                                              \
      for (int k0 = 0; k0 < 256; k0 += 32) {                                           \
        bf16x8 b = *(const bf16x8*)(ub + k0);                                          \
        int gcol = ((((k0 >> 3) + quad) ^ s) << 3);                                    \
        _Pragma("unroll")                                                              \
        for (int m = 0; m < 4; ++m) {                                                  \
          bf16x8 a = *(const bf16x8*)&t1[(m * 16 + l15) * 256 + gcol];                 \
          acc3[m] = MFMA16(a, b, acc3[m]);                                             \
        }                                                                              \
      }                                                                                \
      int col = wave * 64 + (P) * 16 + l15;                                            \
      float bv = bias[l * D_DIM + col];                                                \
      _Pragma("unroll")                                                                \
      for (int m = 0; m < 4; ++m)                                                      \
        _Pragma("unroll")                                                              \
        for (int rg = 0; rg < 4; ++rg) {                                               \
          int row = m * 16 + quad * 4 + rg;                                            \
          long gidx = (rowbase + row) * D_DIM + col;                                   \
          float xin = inputs[gidx];                                                    \
          float x0 = b2f(f2b(xin));                                                    \
          float An = AARR[m][rg] + (acc3[m][rg] + bv);                                 \
          AARR[m][rg] = An;                                                            \
          if (l == L_NUM - 1) {                                                        \
            out[gidx] = xin + x0 * An;                                                 \
          } else {                                                                     \
            xl[xl_addr(row, col)] = f2b(xin + x0 * An);                                \
          }                                                                            \
        }                                                                              \
    }

    PHASE_D_PASS(0, A0)
    PHASE_D_PASS(1, A1)
    PHASE_D_PASS(2, A2)
    PHASE_D_PASS(3, A3)
#undef PHASE_D_PASS

    __syncthreads();   // BARRIER4: xl_new complete; t1 free for next layer's v1
  }
}

extern "C" void kernel_launch(void* const* d_in, const int* in_sizes, int n_in,
                              void* d_out, int out_size, void* d_ws, size_t ws_size,
                              hipStream_t stream) {
  (void)in_sizes; (void)n_in; (void)out_size; (void)ws_size;
  const float* inputs = (const float*)d_in[0];
  const float* U      = (const float*)d_in[1];
  const float* V      = (const float*)d_in[2];
  const float* C      = (const float*)d_in[3];
  const float* gw     = (const float*)d_in[4];
  const float* bias   = (const float*)d_in[5];
  float* out = (float*)d_out;

  ushort* vt = (ushort*)d_ws;          // 3*272*1024 bf16
  ushort* ut = vt + VT_ELEMS;          // 3*1024*256 bf16
  ushort* cb = ut + UT_ELEMS;          // 3*4*64*64  bf16

  pack_all_kernel<<<(PACK_TOTAL + 255) / 256, 256, 0, stream>>>(U, V, C, gw, vt, ut, cb);

  crossnet_fused<<<B_ROWS / BT, TPB, 0, stream>>>(inputs, bias, vt, ut, cb, out);
}